// Round 1
// baseline (322.402 us; speedup 1.0000x reference)
//
#include <hip/hip_runtime.h>
#include <cstddef>

#define BT   8192   // B*T tokens
#define HD   2048   // hidden
#define NS   32     // schemas
#define RDIM 16     // low rank
#define AD   32     // attr dim
#define CAP  2048   // per-(slot,schema) list capacity (expected ~256)

// ---------------- workspace layout ----------------
// [0,256)                      int   cnt[64]            (slot*32 + schema)
// [256, 256+64*CAP*4)          int   tok_list[64][CAP]
// [..,  .. +64*CAP*4)          float cf_list[64][CAP]

__global__ void k_zero(int* __restrict__ cnt) {
    if (threadIdx.x < 64) cnt[threadIdx.x] = 0;
}

// ---------------- router: scores + top2 + gates + schema lists ----------------
// block = 256 thr, 8 tokens. wave w handles schemas w*8..w*8+7 (2 groups of 4),
// K=2048 split across 64 lanes (float4), LDS-transpose reduction.
__global__ __launch_bounds__(256, 2) void k_router(
    const float* __restrict__ h, const float* __restrict__ Wr,
    const float* __restrict__ attr, const float* __restrict__ Wa,
    int* __restrict__ cnt, int* __restrict__ tok_list, float* __restrict__ cf_list)
{
    __shared__ float red[4][64][33];
    __shared__ float sc[8][33];
    const int tid = threadIdx.x;
    const int w = tid >> 6, L = tid & 63;
    const int t0 = blockIdx.x * 8;

    #pragma unroll 1
    for (int g = 0; g < 2; ++g) {
        const int sbase = w * 8 + g * 4;
        float acc[8][4];
        #pragma unroll
        for (int t = 0; t < 8; ++t)
            #pragma unroll
            for (int c = 0; c < 4; ++c) acc[t][c] = 0.f;

        #pragma unroll 1
        for (int i = 0; i < 8; ++i) {
            const int j = 4 * L + 256 * i;
            const float4 wv0 = *(const float4*)(Wr + (size_t)(sbase + 0) * HD + j);
            const float4 wv1 = *(const float4*)(Wr + (size_t)(sbase + 1) * HD + j);
            const float4 wv2 = *(const float4*)(Wr + (size_t)(sbase + 2) * HD + j);
            const float4 wv3 = *(const float4*)(Wr + (size_t)(sbase + 3) * HD + j);
            #pragma unroll
            for (int t = 0; t < 8; ++t) {
                const float4 hv = *(const float4*)(h + (size_t)(t0 + t) * HD + j);
                acc[t][0] += hv.x*wv0.x + hv.y*wv0.y + hv.z*wv0.z + hv.w*wv0.w;
                acc[t][1] += hv.x*wv1.x + hv.y*wv1.y + hv.z*wv1.z + hv.w*wv1.w;
                acc[t][2] += hv.x*wv2.x + hv.y*wv2.y + hv.z*wv2.z + hv.w*wv2.w;
                acc[t][3] += hv.x*wv3.x + hv.y*wv3.y + hv.z*wv3.z + hv.w*wv3.w;
            }
        }
        #pragma unroll
        for (int t = 0; t < 8; ++t)
            #pragma unroll
            for (int c = 0; c < 4; ++c)
                red[w][L][t * 4 + c] = acc[t][c];
        __syncthreads();
        if (L < 32) {
            float ssum = 0.f;
            #pragma unroll 1
            for (int k2 = 0; k2 < 64; ++k2) ssum += red[w][k2][L];
            sc[L >> 2][sbase + (L & 3)] = ssum;   // token row, schema col
        }
        __syncthreads();
    }

    if (tid < 8) {
        const int t = tid;
        float m1 = -1e30f, m2 = -1e30f;
        int i1 = 0, i2 = 0;
        #pragma unroll 1
        for (int sI = 0; sI < NS; ++sI) {   // strict > keeps lowest index on ties (lax.top_k)
            const float v = sc[t][sI];
            if (v > m1) { m2 = m1; i2 = i1; m1 = v; i1 = sI; }
            else if (v > m2) { m2 = v; i2 = sI; }
        }
        float Z = 0.f;
        #pragma unroll 1
        for (int sI = 0; sI < NS; ++sI) Z += __expf(sc[t][sI] - m1);
        const float e2  = __expf(m2 - m1);
        // g = softmax(sc)*mask renormed by (sum + 1e-8): G = e_i / (e1+e2 + 1e-8*Z)
        const float den = 1.f + e2 + 1e-8f * Z;
        const float G1 = 1.f / den, G2 = e2 / den;
        float d1 = 0.f, d2 = 0.f;
        #pragma unroll 1
        for (int d = 0; d < AD; ++d) {
            d1 += attr[i1 * AD + d] * Wa[d];
            d2 += attr[i2 * AD + d] * Wa[d];
        }
        const float aw1 = 1.f / (1.f + __expf(-d1));
        const float aw2 = 1.f / (1.f + __expf(-d2));
        const float mult = 0.9f + 0.2f * (G1 * aw1 + G2 * aw2);
        const float c1 = G1 * mult, c2 = G2 * mult;
        const int gt = t0 + t;
        int p = atomicAdd(cnt + i1, 1);
        if (p < CAP) { tok_list[i1 * CAP + p] = gt; cf_list[i1 * CAP + p] = c1; }
        p = atomicAdd(cnt + NS + i2, 1);
        if (p < CAP) { tok_list[(NS + i2) * CAP + p] = gt; cf_list[(NS + i2) * CAP + p] = c2; }
    }
}

// ---------------- expert pass: one (schema, 16-token chunk) per block ----------------
// stage A: y[t][k] = h[t,:] @ U[s,:,k]  (j-chunked LDS tiles, 4t x 4k register tile,
//          16-way j-split reduced through LDS), y *= cf (gate+mult folded).
// stage B: out[t][j] (+)= sum_k y[t][k] * V[s][k][j]  (V LDS tiles, y in regs).
// slot 0 stores (covers every token exactly once), slot 1 does non-atomic RMW add.
__global__ __launch_bounds__(256, 2) void k_expert(
    const float* __restrict__ h, const float* __restrict__ U, const float* __restrict__ V,
    const int* __restrict__ cnt, const int* __restrict__ tok_list,
    const float* __restrict__ cf_list, float* __restrict__ out, const int slot)
{
    __shared__ float smem[16 * 257 + 4096]; // A: hs[16][257]+us[256][16]; reused: ypart[256][17], vs[16][260]
    __shared__ float ylds[16 * 16];
    __shared__ int   toks_s[16];
    __shared__ float cfs_s[16];

    const int tid = threadIdx.x;
    const int s = blockIdx.x;
    const int base = slot * NS + s;
    int count = cnt[base];
    if (count > CAP) count = CAP;

    float* hs = smem;             // [16][257]
    float* us = smem + 16 * 257;  // [256][16] flat

    const int slot4 = tid & 15, jsub = tid >> 4;   // stage A mapping
    const int tg = slot4 >> 2, kq = slot4 & 3;
    const int w = tid >> 6, L = tid & 63;          // staging mapping
    const int tg2 = tid >> 5, jg = tid & 31;       // stage B mapping

    #pragma unroll 1
    for (int ci = blockIdx.y; ci * 16 < count; ci += gridDim.y) {
        const int nt = min(16, count - ci * 16);
        if (tid < 16) {
            if (tid < nt) {
                toks_s[tid] = tok_list[base * CAP + ci * 16 + tid];
                cfs_s[tid]  = cf_list[base * CAP + ci * 16 + tid];
            } else { toks_s[tid] = 0; cfs_s[tid] = 0.f; }
        }
        __syncthreads();

        // ---------------- stage A ----------------
        float acc[4][4];
        #pragma unroll
        for (int a = 0; a < 4; ++a)
            #pragma unroll
            for (int b = 0; b < 4; ++b) acc[a][b] = 0.f;

        #pragma unroll 1
        for (int c = 0; c < 8; ++c) {          // j chunks of 256
            #pragma unroll
            for (int rr = 0; rr < 4; ++rr) {   // stage h rows (gather)
                const int row = w * 4 + rr;
                float4 hv = {0.f, 0.f, 0.f, 0.f};
                if (row < nt)
                    hv = *(const float4*)(h + (size_t)toks_s[row] * HD + c * 256 + L * 4);
                float* hp = hs + row * 257 + L * 4;
                hp[0] = hv.x; hp[1] = hv.y; hp[2] = hv.z; hp[3] = hv.w;
            }
            const float* Up = U + ((size_t)s * HD + c * 256) * RDIM;  // contiguous 4096 floats
            #pragma unroll
            for (int q = 0; q < 4; ++q)
                *(float4*)(us + (q * 256 + tid) * 4) = *(const float4*)(Up + (q * 256 + tid) * 4);
            __syncthreads();

            const int j0 = jsub * 16;
            #pragma unroll
            for (int jj = 0; jj < 16; ++jj) {
                const float4 uv = *(const float4*)(us + (j0 + jj) * 16 + kq * 4);
                #pragma unroll
                for (int tt = 0; tt < 4; ++tt) {
                    const float hv = hs[(tg * 4 + tt) * 257 + j0 + jj];
                    acc[tt][0] += hv * uv.x;
                    acc[tt][1] += hv * uv.y;
                    acc[tt][2] += hv * uv.z;
                    acc[tt][3] += hv * uv.w;
                }
            }
            __syncthreads();
        }

        // j-split reduction: ypart[256][17] reuses smem
        float* yp = smem;
        #pragma unroll
        for (int m = 0; m < 16; ++m)
            yp[tid * 17 + m] = acc[m >> 2][m & 3];
        __syncthreads();
        {
            const int t = tid >> 4, k = tid & 15;       // one y value per thread
            const int sl = (t >> 2) * 4 + (k >> 2);
            const int m  = (t & 3) * 4 + (k & 3);
            float yv = 0.f;
            #pragma unroll
            for (int js = 0; js < 16; ++js)
                yv += yp[(js * 16 + sl) * 17 + m];
            ylds[t * 16 + k] = yv * cfs_s[t];           // fold gate coeff here
        }
        __syncthreads();

        // ---------------- stage B ----------------
        float yr[2][16];
        #pragma unroll
        for (int tt = 0; tt < 2; ++tt)
            #pragma unroll
            for (int k = 0; k < 16; ++k)
                yr[tt][k] = ylds[(tg2 * 2 + tt) * 16 + k];

        float* vs = smem;   // [16][260]
        #pragma unroll 1
        for (int c = 0; c < 8; ++c) {
            const float* Vp = V + (size_t)s * RDIM * HD + c * 256;
            #pragma unroll
            for (int rr = 0; rr < 4; ++rr) {
                const int k = w * 4 + rr;
                *(float4*)(vs + k * 260 + L * 4) = *(const float4*)(Vp + (size_t)k * HD + L * 4);
            }
            __syncthreads();

            float a0[2][4], a1[2][4];
            #pragma unroll
            for (int tt = 0; tt < 2; ++tt)
                #pragma unroll
                for (int u = 0; u < 4; ++u) { a0[tt][u] = 0.f; a1[tt][u] = 0.f; }
            #pragma unroll
            for (int k = 0; k < 16; ++k) {
                const float4 v0 = *(const float4*)(vs + k * 260 + jg * 8);
                const float4 v1 = *(const float4*)(vs + k * 260 + jg * 8 + 4);
                #pragma unroll
                for (int tt = 0; tt < 2; ++tt) {
                    const float f = yr[tt][k];
                    a0[tt][0] += f * v0.x; a0[tt][1] += f * v0.y;
                    a0[tt][2] += f * v0.z; a0[tt][3] += f * v0.w;
                    a1[tt][0] += f * v1.x; a1[tt][1] += f * v1.y;
                    a1[tt][2] += f * v1.z; a1[tt][3] += f * v1.w;
                }
            }
            #pragma unroll
            for (int tt = 0; tt < 2; ++tt) {
                const int row = tg2 * 2 + tt;
                if (row < nt) {
                    float* op = out + (size_t)toks_s[row] * HD + c * 256 + jg * 8;
                    if (slot == 0) {
                        *(float4*)(op)     = make_float4(a0[tt][0], a0[tt][1], a0[tt][2], a0[tt][3]);
                        *(float4*)(op + 4) = make_float4(a1[tt][0], a1[tt][1], a1[tt][2], a1[tt][3]);
                    } else {
                        float4 o0 = *(const float4*)(op);
                        float4 o1 = *(const float4*)(op + 4);
                        o0.x += a0[tt][0]; o0.y += a0[tt][1]; o0.z += a0[tt][2]; o0.w += a0[tt][3];
                        o1.x += a1[tt][0]; o1.y += a1[tt][1]; o1.z += a1[tt][2]; o1.w += a1[tt][3];
                        *(float4*)(op)     = o0;
                        *(float4*)(op + 4) = o1;
                    }
                }
            }
            __syncthreads();
        }
    }
}

extern "C" void kernel_launch(void* const* d_in, const int* in_sizes, int n_in,
                              void* d_out, int out_size, void* d_ws, size_t ws_size,
                              hipStream_t stream)
{
    const float* h    = (const float*)d_in[0];
    const float* Wr   = (const float*)d_in[1];
    const float* U    = (const float*)d_in[2];
    const float* V    = (const float*)d_in[3];
    const float* attr = (const float*)d_in[4];
    const float* Wa   = (const float*)d_in[5];
    float* out = (float*)d_out;

    int*   cnt      = (int*)d_ws;
    int*   tok_list = (int*)((char*)d_ws + 256);
    float* cf_list  = (float*)((char*)d_ws + 256 + (size_t)64 * CAP * sizeof(int));

    hipLaunchKernelGGL(k_zero,   dim3(1),          dim3(64),  0, stream, cnt);
    hipLaunchKernelGGL(k_router, dim3(BT / 8),     dim3(256), 0, stream,
                       h, Wr, attr, Wa, cnt, tok_list, cf_list);
    hipLaunchKernelGGL(k_expert, dim3(NS, 32),     dim3(256), 0, stream,
                       h, U, V, cnt, tok_list, cf_list, out, 0);
    hipLaunchKernelGGL(k_expert, dim3(NS, 32),     dim3(256), 0, stream,
                       h, U, V, cnt, tok_list, cf_list, out, 1);
}